// Round 5
// baseline (207.286 us; speedup 1.0000x reference)
//
#include <hip/hip_runtime.h>
#include <math.h>

#define PSTR 37   // part[] col stride (floats): 37 mod 32 = 5, gcd(5,32)=1 -> 2-way banks (free)

template<int N> struct IC { static constexpr int v = N; };

__device__ __forceinline__ float fast_atan2f(float y, float x) {
    float ax = fabsf(x), ay = fabsf(y);
    float mx = fmaxf(ax, ay);
    float mn = fminf(ax, ay);
    float a = mn * __builtin_amdgcn_rcpf(fmaxf(mx, 1e-30f));
    float s = a * a;
    float r = fmaf(s, fmaf(s, fmaf(s, fmaf(s, fmaf(s, -0.0117212f, 0.05265332f),
                    -0.11643287f), 0.19354346f), -0.33262347f), 0.99997726f) * a;
    r = (ay > ax) ? (1.57079637f - r) : r;
    r = (x < 0.0f) ? (3.14159274f - r) : r;
    return copysignf(r, y);
}

// 2 waves/block: wave0 rows 0..31, wave1 rows 32..64. lane = column.
// Histogram accumulated via LDS ds_add_f32 into part[col][sy*9 + slot],
// slot = b0 and b0+1 (slot 8 aliases bin 0, folded before pooling).
__global__ __launch_bounds__(128, 6)
void sift_kernel(const float* __restrict__ in, float* __restrict__ out) {
    __shared__ float part[65 * PSTR];
    __shared__ float gauss[65];
    __shared__ float c64buf[2][36];     // col-64 halo rows per wave: k -> col64[clamp(r0-1+k)]

    const int tid  = threadIdx.x;
    const int lane = tid & 63;
    const int wid  = tid >> 6;
    const int m    = blockIdx.x;
    const int bc   = m >> 6;
    const int ij   = m & 63;
    const float* src = in + (size_t)bc * (520 * 520) + (ij >> 3) * (65 * 520) + (ij & 7) * 65;

    const int r0 = wid ? 32 : 0;
    const int nr = wid ? 33 : 32;

    // ---- zero partials ----
    for (int k = tid; k < 65 * PSTR; k += 128) part[k] = 0.0f;

    // ---- stage col-64 halo (proven R3 mechanism) ----
    if (lane < 35) {
        int rr = r0 - 1 + lane; rr = (rr < 0) ? 0 : ((rr > 64) ? 64 : rr);
        c64buf[wid][lane] = src[rr * 520 + 64];
    }

    // ---- gaussian -> LDS (both waves compute identical values) ----
    {
        float dd = (float)(lane - 32);
        float e  = __expf(-(dd * dd) * (1.0f / 4225.0f));
        float ssum = e;
        #pragma unroll
        for (int off = 32; off > 0; off >>= 1) ssum += __shfl_xor(ssum, off, 64);
        const float e64 = __expf(-1024.0f / 4225.0f);
        float inv = 1.0f / (ssum + e64);
        gauss[lane] = e * inv;
        if (lane == 0) gauss[64] = e64 * inv;
    }
    __syncthreads();

    const float GC = 0.5f * gauss[lane];   // column gaussian, folds the 0.5 gradient scale

    // ---- rolling row registers with 3-deep prefetch ----
    auto LROW = [&](int rr) {
        rr = (rr < 0) ? 0 : ((rr > 64) ? 64 : rr);
        return src[rr * 520 + lane];
    };
    float xu = LROW(r0 - 1), xc = LROW(r0), xd = LROW(r0 + 1);
    float n0 = LROW(r0 + 2), n1 = LROW(r0 + 3);

    float* pbase = &part[lane * PSTR];

    auto body = [&](int r, auto S0_, auto S1_) {
        constexpr int S0 = decltype(S0_)::v;
        constexpr int S1 = decltype(S1_)::v;
        float c64r = c64buf[wid][r - r0 + 1];   // col64[r] (uniform LDS read)
        float gw   = gauss[r] * GC;
        float xl = __shfl_up(xc, 1);   if (lane == 0)  xl = xc;
        float xr = __shfl_down(xc, 1); if (lane == 63) xr = c64r;
        float dx = xr - xl;
        float dy = xd - xu;
        float magw = sqrtf(fmaf(dx, dx, fmaf(dy, dy, 4e-10f))) * gw;
        float ang = fast_atan2f(dy, dx + 2e-10f);
        float o   = fmaf(ang, 1.27323954f, 8.0f);    // in (4,12]
        int bi = (int)o;
        float wo1 = o - (float)bi;
        int b0 = bi & 7;
        float q1 = wo1 * magw;
        float q0 = magw - q1;
        float* pb = pbase + b0;                      // slot b0; b0+1 is imm offset +4
        float u0 = (float)(r - (16 * S0 - 6));
        float W0 = (13.0f - fabsf(u0 - 12.5f)) * (1.0f / 13.0f);
        atomicAdd(pb + S0 * 9,     q0 * W0);
        atomicAdd(pb + S0 * 9 + 1, q1 * W0);
        if constexpr (S1 >= 0) {
            float u1 = (float)(r - (16 * S1 - 6));
            float W1 = (13.0f - fabsf(u1 - 12.5f)) * (1.0f / 13.0f);
            atomicAdd(pb + S1 * 9,     q0 * W1);
            atomicAdd(pb + S1 * 9 + 1, q1 * W1);
        }
        xu = xc; xc = xd; xd = n0; n0 = n1; n1 = LROW(r + 4);
    };

    // row windows: sy0=[0,19] sy1=[10,35] sy2=[26,51] sy3=[42,64]
    if (wid == 0) {
        for (int r = 0;  r < 10; ++r) body(r, IC<0>{}, IC<-1>{});
        for (int r = 10; r < 20; ++r) body(r, IC<0>{}, IC<1>{});
        for (int r = 20; r < 26; ++r) body(r, IC<1>{}, IC<-1>{});
        for (int r = 26; r < 32; ++r) body(r, IC<1>{}, IC<2>{});
    } else {
        for (int r = 32; r < 36; ++r) body(r, IC<1>{}, IC<2>{});
        for (int r = 36; r < 42; ++r) body(r, IC<2>{}, IC<-1>{});
        for (int r = 42; r < 52; ++r) body(r, IC<2>{}, IC<3>{});
        for (int r = 52; r < 65; ++r) body(r, IC<3>{}, IC<-1>{});
    }

    // ---- column 64: lane k -> pixel row r0+k (proven R3-style LDS halo reads) ----
    if (lane < nr) {
        int r = r0 + lane;
        float xu64 = c64buf[wid][lane];        // col64[r-1] (clamped at r=0)
        float xc64 = c64buf[wid][lane + 1];    // col64[r]
        float xd64 = c64buf[wid][lane + 2];    // col64[r+1] (clamped at r=64)
        float xl63 = src[r * 520 + 63];
        float dx = xc64 - xl63;                // right neighbor replicates to xc64
        float dy = xd64 - xu64;
        float magw = sqrtf(fmaf(dx, dx, fmaf(dy, dy, 4e-10f))) * (gauss[r] * (0.5f * gauss[64]));
        float ang = fast_atan2f(dy, dx + 2e-10f);
        float o   = fmaf(ang, 1.27323954f, 8.0f);
        int bi = (int)o;
        float wo1 = o - (float)bi;
        int b0 = bi & 7;
        float q1 = wo1 * magw;
        float q0 = magw - q1;
        float* eb = &part[64 * PSTR + b0];
        int syA = (r + 6) >> 4; if (syA > 3) syA = 3;
        float uA = (float)(r - 16 * syA + 6);
        float wA = (13.0f - fabsf(uA - 12.5f)) * (1.0f / 13.0f);
        atomicAdd(eb + syA * 9,     q0 * wA);
        atomicAdd(eb + syA * 9 + 1, q1 * wA);
        int syB = syA - 1;
        if (syB >= 0) {
            float uB = (float)(r - 16 * syB + 6);
            float wB = (13.0f - fabsf(uB - 12.5f)) * (1.0f / 13.0f);
            if (wB > 0.0f) {
                atomicAdd(eb + syB * 9,     q0 * wB);
                atomicAdd(eb + syB * 9 + 1, q1 * wB);
            }
        }
    }
    __syncthreads();

    // ---- fold slot 8 (bin-0 overflow) into slot 0 ----
    for (int idx = tid; idx < 65 * 4; idx += 128) {
        int col = idx >> 2, sy = idx & 3;
        part[col * PSTR + sy * 9] += part[col * PSTR + sy * 9 + 8];
    }
    __syncthreads();

    // ---- column pooling + double-normalize + store (wave 0) ----
    if (wid == 0) {
        float v[2];
        #pragma unroll
        for (int h = 0; h < 2; ++h) {
            int o  = lane + h * 64;
            int a  = o >> 4;
            int sy = (o >> 2) & 3;
            int sx = o & 3;
            float s = 0.0f;
            #pragma unroll 2
            for (int k = 0; k < 26; ++k) {
                int c = sx * 16 - 6 + k;
                if ((unsigned)c <= 64u) {
                    float wc = (13.0f - fabsf((float)k - 12.5f)) * (1.0f / 13.0f);
                    s = fmaf(wc, part[c * PSTR + sy * 9 + a], s);
                }
            }
            v[h] = s;
        }
        float ss = v[0] * v[0] + v[1] * v[1];
        #pragma unroll
        for (int off = 32; off > 0; off >>= 1) ss += __shfl_xor(ss, off, 64);
        float sc = 1.0f / fmaxf(sqrtf(ss), 1e-12f);
        v[0] = fminf(fmaxf(v[0] * sc, 0.0f), 0.2f);
        v[1] = fminf(fmaxf(v[1] * sc, 0.0f), 0.2f);
        ss = v[0] * v[0] + v[1] * v[1];
        #pragma unroll
        for (int off = 32; off > 0; off >>= 1) ss += __shfl_xor(ss, off, 64);
        sc = 1.0f / fmaxf(sqrtf(ss), 1e-12f);
        out[(size_t)m * 128 + lane]      = v[0] * sc;
        out[(size_t)m * 128 + lane + 64] = v[1] * sc;
    }
}

extern "C" void kernel_launch(void* const* d_in, const int* in_sizes, int n_in,
                              void* d_out, int out_size, void* d_ws, size_t ws_size,
                              hipStream_t stream) {
    const float* in = (const float*)d_in[0];
    float* out = (float*)d_out;
    sift_kernel<<<3072, 128, 0, stream>>>(in, out);
}

// Round 6
// 126.330 us; speedup vs baseline: 1.6408x; 1.6408x over previous
//
#include <hip/hip_runtime.h>
#include <math.h>

#define PSTR 33   // part[] col stride: 33 mod 32 = 1 -> lanes hit distinct banks

__device__ __forceinline__ float fast_atan2f(float y, float x) {
    float ax = fabsf(x), ay = fabsf(y);
    float mx = fmaxf(ax, ay);
    float mn = fminf(ax, ay);
    float a = mn * __builtin_amdgcn_rcpf(fmaxf(mx, 1e-30f));
    float s = a * a;
    float r = fmaf(s, fmaf(s, fmaf(s, fmaf(s, fmaf(s, -0.0117212f, 0.05265332f),
                    -0.11643287f), 0.19354346f), -0.33262347f), 0.99997726f) * a;
    r = (ay > ax) ? (1.57079637f - r) : r;
    r = (x < 0.0f) ? (3.14159274f - r) : r;
    return copysignf(r, y);
}

// 4 waves/patch: wave w owns rows [16w,16w+16) (+row 64 for wave 3). lane = column.
// Patch staged in LDS (coalesced, one latency exposure); register accumulators
// with compile-time row-pool weights (R3-proven); cross-wave merge via LDS atomics.
__global__ __launch_bounds__(256, 6)
void sift_kernel(const float* __restrict__ in, float* __restrict__ out) {
    __shared__ float patch[65 * 65];   // 16.9 KB, stride 65 (row reads are lane-consecutive)
    __shared__ float part[65 * PSTR]; // 8.6 KB  [column][sy*8 + a]
    __shared__ float gauss[65];

    const int tid  = threadIdx.x;
    const int lane = tid & 63;
    const int wid  = tid >> 6;
    const int m    = blockIdx.x;
    const int bc   = m >> 6;
    const int ij   = m & 63;
    const float* src = in + (size_t)bc * (520 * 520) + (ij >> 3) * (65 * 520) + (ij & 7) * 65;

    // ---- stage patch to LDS (coalesced; 17 iterations of 256 threads) ----
    for (int k = tid; k < 65 * 65; k += 256) {
        int y = k / 65;
        int x = k - y * 65;
        patch[k] = src[y * 520 + x];
    }
    // ---- zero partials ----
    for (int k = tid; k < 65 * PSTR; k += 256) part[k] = 0.0f;
    // ---- gaussian (wave 0): sigma = 65/sqrt(2) -> 2*sigma^2 = 4225 ----
    if (wid == 0) {
        float dd = (float)(lane - 32);
        float e  = __expf(-(dd * dd) * (1.0f / 4225.0f));
        float ssum = e;
        #pragma unroll
        for (int off = 32; off > 0; off >>= 1) ssum += __shfl_xor(ssum, off, 64);
        const float e64 = __expf(-1024.0f / 4225.0f);
        float inv = 1.0f / (ssum + e64);
        gauss[lane] = e * inv;
        if (lane == 0) gauss[64] = e64 * inv;
    }
    __syncthreads();

    const float GC = 0.5f * gauss[lane];   // column gaussian (0.5 grad scale folded)
    const int r0 = wid * 16;

    float acc0[8], acc1[8], acc2[8];
    #pragma unroll
    for (int a = 0; a < 8; ++a) { acc0[a] = 0.0f; acc1[a] = 0.0f; acc2[a] = 0.0f; }

    // rolling rows from LDS
    float xu = patch[(wid ? r0 - 1 : 0) * 65 + lane];
    float xc = patch[r0 * 65 + lane];
    float xd = patch[(r0 + 1) * 65 + lane];

    #pragma unroll
    for (int k = 0; k < 16; ++k) {
        const int r = r0 + k;
        const float W0 = (3.5f - (float)k) * (1.0f / 13.0f);                 // sy=wid-1 (k<=3)
        const float W1 = (13.0f - fabsf((float)k - 6.5f)) * (1.0f / 13.0f);  // sy=wid
        const float W2 = ((float)k - 9.5f) * (1.0f / 13.0f);                 // sy=wid+1 (k>=10)
        float c64r = patch[r * 65 + 64];     // uniform -> broadcast
        float gw   = gauss[r] * GC;
        float xl = __shfl_up(xc, 1);   if (lane == 0)  xl = xc;
        float xr = __shfl_down(xc, 1); if (lane == 63) xr = c64r;
        float dx = xr - xl;
        float dy = xd - xu;
        float magw = sqrtf(fmaf(dx, dx, fmaf(dy, dy, 4e-10f))) * gw;
        float ang = fast_atan2f(dy, dx + 2e-10f);
        float o   = fmaf(ang, 1.27323954f, 8.0f);     // in (4,12]
        int bi = (int)o;
        float wo1 = o - (float)bi;
        int b0 = bi & 7;
        int b1 = (bi + 1) & 7;
        float q1 = wo1 * magw;
        float q0 = magw - q1;
        #pragma unroll
        for (int a = 0; a < 8; ++a) {
            float s = (a == b0) ? q0 : ((a == b1) ? q1 : 0.0f);
            if (k <= 3) {
                acc0[a] = fmaf(s, W0, acc0[a]);
                acc1[a] = fmaf(s, W1, acc1[a]);
            } else if (k < 10) {
                acc1[a] = fmaf(s, W1, acc1[a]);
            } else {
                acc1[a] = fmaf(s, W1, acc1[a]);
                acc2[a] = fmaf(s, W2, acc2[a]);
            }
        }
        xu = xc; xc = xd;
        int rn = (r + 2 <= 64) ? r + 2 : 64;
        xd = patch[rn * 65 + lane];
    }
    // ---- wave 3 extra: row 64 (sy=3 only, weight (13-|22-12.5|)/13 = 3.5/13) ----
    if (wid == 3) {
        const float W1 = 3.5f * (1.0f / 13.0f);
        float c64r = patch[64 * 65 + 64];
        float gw   = gauss[64] * GC;
        float xl = __shfl_up(xc, 1);   if (lane == 0)  xl = xc;
        float xr = __shfl_down(xc, 1); if (lane == 63) xr = c64r;
        float dx = xr - xl;
        float dy = xd - xu;   // xu=row63, xd=row64 (replicate)
        float magw = sqrtf(fmaf(dx, dx, fmaf(dy, dy, 4e-10f))) * gw;
        float ang = fast_atan2f(dy, dx + 2e-10f);
        float o   = fmaf(ang, 1.27323954f, 8.0f);
        int bi = (int)o;
        float wo1 = o - (float)bi;
        int b0 = bi & 7;
        int b1 = (bi + 1) & 7;
        float q1 = wo1 * magw;
        float q0 = magw - q1;
        #pragma unroll
        for (int a = 0; a < 8; ++a) {
            float s = (a == b0) ? q0 : ((a == b1) ? q1 : 0.0f);
            acc1[a] = fmaf(s, W1, acc1[a]);
        }
    }

    // ---- flush accumulators (cross-wave merge; few atomics, negligible) ----
    {
        const int colbase = lane * PSTR;
        if (wid > 0) {
            #pragma unroll
            for (int a = 0; a < 8; ++a)
                atomicAdd(&part[colbase + (wid - 1) * 8 + a], acc0[a]);
        }
        #pragma unroll
        for (int a = 0; a < 8; ++a)
            atomicAdd(&part[colbase + wid * 8 + a], acc1[a]);
        if (wid < 3) {
            #pragma unroll
            for (int a = 0; a < 8; ++a)
                atomicAdd(&part[colbase + (wid + 1) * 8 + a], acc2[a]);
        }
    }

    // ---- column 64: lane k -> pixel row r0+k (reads from LDS patch) ----
    {
        const int nr = (wid == 3) ? 17 : 16;
        if (lane < nr) {
            int r = r0 + lane;
            float xu64 = patch[((r > 0) ? r - 1 : 0) * 65 + 64];
            float xc64 = patch[r * 65 + 64];
            float xd64 = patch[((r < 64) ? r + 1 : 64) * 65 + 64];
            float xl63 = patch[r * 65 + 63];
            float dx = xc64 - xl63;              // right neighbor replicates to xc64
            float dy = xd64 - xu64;
            float magw = sqrtf(fmaf(dx, dx, fmaf(dy, dy, 4e-10f))) * (gauss[r] * (0.5f * gauss[64]));
            float ang = fast_atan2f(dy, dx + 2e-10f);
            float o   = fmaf(ang, 1.27323954f, 8.0f);
            int bi = (int)o;
            float wo1 = o - (float)bi;
            int b0 = bi & 7;
            int b1 = (bi + 1) & 7;
            float q1 = wo1 * magw;
            float q0 = magw - q1;
            float* eb = &part[64 * PSTR];
            int syA = (r + 6) >> 4; if (syA > 3) syA = 3;
            float uA = (float)(r - 16 * syA + 6);
            float wA = (13.0f - fabsf(uA - 12.5f)) * (1.0f / 13.0f);
            atomicAdd(eb + syA * 8 + b0, q0 * wA);
            atomicAdd(eb + syA * 8 + b1, q1 * wA);
            int syB = syA - 1;
            if (syB >= 0) {
                float uB = (float)(r - 16 * syB + 6);
                float wB = (13.0f - fabsf(uB - 12.5f)) * (1.0f / 13.0f);
                if (wB > 0.0f) {
                    atomicAdd(eb + syB * 8 + b0, q0 * wB);
                    atomicAdd(eb + syB * 8 + b1, q1 * wB);
                }
            }
        }
    }
    __syncthreads();

    // ---- column pooling + double-normalize + store (wave 0) ----
    if (wid == 0) {
        float v[2];
        #pragma unroll
        for (int h = 0; h < 2; ++h) {
            int o  = lane + h * 64;
            int a  = o >> 4;
            int sy = (o >> 2) & 3;
            int sx = o & 3;
            float s = 0.0f;
            #pragma unroll 2
            for (int k = 0; k < 26; ++k) {
                int c = sx * 16 - 6 + k;
                if ((unsigned)c <= 64u) {
                    float wc = (13.0f - fabsf((float)k - 12.5f)) * (1.0f / 13.0f);
                    s = fmaf(wc, part[c * PSTR + sy * 8 + a], s);
                }
            }
            v[h] = s;
        }
        float ss = v[0] * v[0] + v[1] * v[1];
        #pragma unroll
        for (int off = 32; off > 0; off >>= 1) ss += __shfl_xor(ss, off, 64);
        float sc = 1.0f / fmaxf(sqrtf(ss), 1e-12f);
        v[0] = fminf(fmaxf(v[0] * sc, 0.0f), 0.2f);
        v[1] = fminf(fmaxf(v[1] * sc, 0.0f), 0.2f);
        ss = v[0] * v[0] + v[1] * v[1];
        #pragma unroll
        for (int off = 32; off > 0; off >>= 1) ss += __shfl_xor(ss, off, 64);
        sc = 1.0f / fmaxf(sqrtf(ss), 1e-12f);
        out[(size_t)m * 128 + lane]      = v[0] * sc;
        out[(size_t)m * 128 + lane + 64] = v[1] * sc;
    }
}

extern "C" void kernel_launch(void* const* d_in, const int* in_sizes, int n_in,
                              void* d_out, int out_size, void* d_ws, size_t ws_size,
                              hipStream_t stream) {
    const float* in = (const float*)d_in[0];
    float* out = (float*)d_out;
    sift_kernel<<<3072, 256, 0, stream>>>(in, out);
}